// Round 8
// baseline (2498.301 us; speedup 1.0000x reference)
//
#include <hip/hip_runtime.h>
#include <hip/hip_bf16.h>
#include <math.h>

#define DMODEL 256
#define PWAYS  4096
#define TOPK   4
#define HMAX   1280
#define NTOK   2048   // B*S = 8*256
#define FSLOTS 16     // freq partial-sum slots (256 KB)

__device__ __forceinline__ float gelu_exact(float z) {
    return 0.5f * z * (1.0f + erff(z * 0.70710678118654752440f));
}

// ---------------- zero pathway-weight output region + freq partials ----------------
__global__ void k_zero(float* __restrict__ pwout, float* __restrict__ freq_part) {
    const int i = blockIdx.x * 256 + threadIdx.x;
    const int stride = gridDim.x * 256;
    for (int j = i; j < NTOK * PWAYS; j += stride) pwout[j] = 0.0f;
    for (int j = i; j < FSLOTS * PWAYS; j += stride) freq_part[j] = 0.0f;
}

// ---- fused router(3 layers) + softmax + top-4 + pathway scatter + freq partials ----
// 4 tokens per block, 256 threads. h1/h2 in LDS; scores in registers (sv[4][16]).
__global__ void __launch_bounds__(256) k_router_select(
    const float* __restrict__ x,
    const float* __restrict__ rw1, const float* __restrict__ rb1,
    const float* __restrict__ rw2, const float* __restrict__ rb2,
    const float* __restrict__ rw3, const float* __restrict__ rb3,
    const float* __restrict__ temp, float* __restrict__ freq_part,
    int* __restrict__ top_idx, float* __restrict__ top_vals, float* __restrict__ pw_out) {
    __shared__ float xs[4][DMODEL];
    __shared__ float h1s[4][DMODEL];
    __shared__ float h2s[4][128];
    __shared__ float red[256];
    __shared__ int redi[256];
    __shared__ int sel[TOPK];
    __shared__ float selv[TOPK];
    const int tid = threadIdx.x;
    const int n0 = blockIdx.x * 4;

    for (int idx = tid; idx < 4 * DMODEL; idx += 256)
        xs[idx >> 8][idx & 255] = x[(size_t)n0 * DMODEL + idx];
    __syncthreads();

    {   // layer 1: [4,256]@[256,256]+b, gelu
        float bias = rb1[tid];
        float a0 = bias, a1 = bias, a2 = bias, a3 = bias;
        for (int c = 0; c < DMODEL; c++) {
            float wv = rw1[c * DMODEL + tid];
            a0 += xs[0][c] * wv; a1 += xs[1][c] * wv;
            a2 += xs[2][c] * wv; a3 += xs[3][c] * wv;
        }
        h1s[0][tid] = gelu_exact(a0); h1s[1][tid] = gelu_exact(a1);
        h1s[2][tid] = gelu_exact(a2); h1s[3][tid] = gelu_exact(a3);
    }
    __syncthreads();

    {   // layer 2: [4,256]@[256,128]+b, gelu
        const int col = tid & 127;
        const int pr = tid >> 7;
        float bias = rb2[col];
        float b0 = bias, b1 = bias;
        for (int c = 0; c < DMODEL; c++) {
            float wv = rw2[c * 128 + col];
            b0 += h1s[2 * pr + 0][c] * wv;
            b1 += h1s[2 * pr + 1][c] * wv;
        }
        h2s[2 * pr + 0][col] = gelu_exact(b0);
        h2s[2 * pr + 1][col] = gelu_exact(b1);
    }
    __syncthreads();

    // layer 3 scores: sv[t][i] for pathway p = tid + i*256
    float sv[4][16];
#pragma unroll
    for (int i = 0; i < 16; i++) {
        float bias = rb3[tid + i * 256];
#pragma unroll
        for (int t = 0; t < 4; t++) sv[t][i] = bias;
    }
    for (int c = 0; c < 128; c++) {
        const float hv0 = h2s[0][c], hv1 = h2s[1][c], hv2 = h2s[2][c], hv3 = h2s[3][c];
        const float* wr = rw3 + (size_t)c * PWAYS + tid;
#pragma unroll
        for (int i = 0; i < 16; i++) {
            float wv = wr[i * 256];
            sv[0][i] += hv0 * wv;
            sv[1][i] += hv1 * wv;
            sv[2][i] += hv2 * wv;
            sv[3][i] += hv3 * wv;
        }
    }

    const float invT = 1.0f / temp[0];
    float psum[16];
#pragma unroll
    for (int i = 0; i < 16; i++) psum[i] = 0.0f;

    for (int t = 0; t < 4; t++) {
        const int n = n0 + t;
        float lmax = -3.402823466e38f;
#pragma unroll
        for (int i = 0; i < 16; i++) lmax = fmaxf(lmax, sv[t][i]);
        red[tid] = lmax; __syncthreads();
        for (int s = 128; s > 0; s >>= 1) {
            if (tid < s) red[tid] = fmaxf(red[tid], red[tid + s]);
            __syncthreads();
        }
        const float m = red[0];
        __syncthreads();

        float ee[16];
        float s1 = 0.f, sT = 0.f;
#pragma unroll
        for (int i = 0; i < 16; i++) {
            float d = sv[t][i] - m;
            ee[i] = expf(d);
            s1 += ee[i];
            sT += expf(d * invT);
        }
        red[tid] = s1; __syncthreads();
        for (int s = 128; s > 0; s >>= 1) { if (tid < s) red[tid] += red[tid + s]; __syncthreads(); }
        const float sum1 = red[0];
        __syncthreads();
        red[tid] = sT; __syncthreads();
        for (int s = 128; s > 0; s >>= 1) { if (tid < s) red[tid] += red[tid + s]; __syncthreads(); }
        const float sumT = red[0];
        __syncthreads();

        const float inv_s1 = 1.0f / sum1;
#pragma unroll
        for (int i = 0; i < 16; i++) psum[i] += ee[i] * inv_s1;   // no-temp probs -> freq

        // top-4 on raw scores; ties -> lower index (matches jax top_k)
        for (int r = 0; r < TOPK; r++) {
            float bv = -3.402823466e38f;
            int bi = PWAYS;
#pragma unroll
            for (int i = 0; i < 16; i++) {
                int p = tid + i * 256;
                bool skip = false;
                for (int u = 0; u < r; u++) if (sel[u] == p) skip = true;
                if (!skip && sv[t][i] > bv) { bv = sv[t][i]; bi = p; }
            }
            red[tid] = bv; redi[tid] = bi; __syncthreads();
            for (int s = 128; s > 0; s >>= 1) {
                if (tid < s) {
                    if (red[tid + s] > red[tid] ||
                        (red[tid + s] == red[tid] && redi[tid + s] < redi[tid])) {
                        red[tid] = red[tid + s]; redi[tid] = redi[tid + s];
                    }
                }
                __syncthreads();
            }
            if (tid == 0) { sel[r] = redi[0]; selv[r] = red[0]; }
            __syncthreads();
        }

        if (tid == 0) {
            float tv[TOPK];
            float wsum = 1e-8f;
#pragma unroll
            for (int k2 = 0; k2 < TOPK; k2++) {
                tv[k2] = expf((selv[k2] - m) * invT) / sumT;   // temp-softmax prob
                wsum += tv[k2];
            }
            float invw = 1.0f / wsum;
#pragma unroll
            for (int k2 = 0; k2 < TOPK; k2++) {
                top_idx[n * TOPK + k2] = sel[k2];
                top_vals[n * TOPK + k2] = tv[k2];
                pw_out[(size_t)n * PWAYS + sel[k2]] = tv[k2] * invw;
            }
        }
        __syncthreads();
    }

    float* fp = freq_part + (size_t)(blockIdx.x & (FSLOTS - 1)) * PWAYS;
#pragma unroll
    for (int i = 0; i < 16; i++) atomicAdd(&fp[tid + i * 256], psum[i]);
}

// ---------------- freq reduce + glbl_loss = P * var(freq, ddof=1) ----------------
__global__ void k_freq_loss(const float* __restrict__ freq_part, float* __restrict__ out_loss) {
    __shared__ float fl[PWAYS];
    __shared__ float red[256];
    const int tid = threadIdx.x;
    for (int p = tid; p < PWAYS; p += 256) {
        float s = 0.f;
        for (int sl = 0; sl < FSLOTS; sl++) s += freq_part[(size_t)sl * PWAYS + p];
        fl[p] = s * (1.0f / NTOK);
    }
    __syncthreads();
    float s = 0.f;
    for (int p = tid; p < PWAYS; p += 256) s += fl[p];
    red[tid] = s; __syncthreads();
    for (int st = 128; st > 0; st >>= 1) { if (tid < st) red[tid] += red[tid + st]; __syncthreads(); }
    const float mu = red[0] * (1.0f / PWAYS);
    __syncthreads();
    float ss = 0.f;
    for (int p = tid; p < PWAYS; p += 256) {
        float d = fl[p] - mu;
        ss += d * d;
    }
    red[tid] = ss; __syncthreads();
    for (int st = 128; st > 0; st >>= 1) { if (tid < st) red[tid] += red[tid + st]; __syncthreads(); }
    if (tid == 0)
        out_loss[0] = (float)PWAYS * red[0] / (float)(PWAYS - 1);
}

// ------- fused expert pipeline: one block per token, 256 threads (one col) -------
__global__ void __launch_bounds__(256) k_experts(
    const float* __restrict__ x,
    const float* __restrict__ pw, const float* __restrict__ pb,
    const float* __restrict__ pg, const float* __restrict__ pbb,
    const float* __restrict__ mw1, const float* __restrict__ mb1,
    const float* __restrict__ mw2, const float* __restrict__ mb2,
    const float* __restrict__ qw, const float* __restrict__ qb,
    const float* __restrict__ qg, const float* __restrict__ qbb,
    const int* __restrict__ top_idx, const float* __restrict__ top_vals,
    float* __restrict__ out) {
    __shared__ float xs[DMODEL];
    __shared__ float xpre[DMODEL];
    __shared__ float mid[HMAX];
    __shared__ float xmlp[DMODEL];
    __shared__ float red[256];
    const int n = blockIdx.x;
    const int tid = threadIdx.x;

    xs[tid] = x[(size_t)n * DMODEL + tid];
    __syncthreads();

    float outacc = 0.f;
    for (int k = 0; k < TOPK; k++) {
        const int idx = top_idx[n * TOPK + k];
        const float tval = top_vals[n * TOPK + k];
        const int ei = idx >> 8;          // pre expert
        const int ej = (idx >> 4) & 15;   // mlp expert
        const int eq = idx & 15;          // post expert

        // ---- pre: Linear + LN + act ----
        {
            const float* W = pw + (size_t)ei * DMODEL * DMODEL + tid;
            float acc = pb[ei * DMODEL + tid];
#pragma unroll 8
            for (int c = 0; c < DMODEL; c++) acc += xs[c] * W[c * DMODEL];
            red[tid] = acc; __syncthreads();
            for (int s = 128; s > 0; s >>= 1) { if (tid < s) red[tid] += red[tid + s]; __syncthreads(); }
            float mu = red[0] * (1.0f / DMODEL);
            __syncthreads();
            float dd = acc - mu;
            red[tid] = dd * dd; __syncthreads();
            for (int s = 128; s > 0; s >>= 1) { if (tid < s) red[tid] += red[tid + s]; __syncthreads(); }
            float var = red[0] * (1.0f / DMODEL);
            __syncthreads();
            float y = dd * rsqrtf(var + 1e-5f) * pg[ei * DMODEL + tid] + pbb[ei * DMODEL + tid];
            const int am = ei % 3;
            y = (am == 0) ? gelu_exact(y) : (am == 1 ? fmaxf(y, 0.f) : tanhf(y));
            xpre[tid] = y;
            __syncthreads();
        }

        // ---- mlp: variable hidden width ----
        const int hid = DMODEL * (2 + (ej >> 2));
        {
            const float* W1 = mw1 + (size_t)ej * DMODEL * HMAX;
            for (int h = tid; h < hid; h += 256) {
                float a = mb1[ej * HMAX + h];
#pragma unroll 8
                for (int c = 0; c < DMODEL; c++) a += xpre[c] * W1[(size_t)c * HMAX + h];
                a = ((ej & 1) == 0) ? gelu_exact(a) : fmaxf(a, 0.f);
                mid[h] = a;
            }
            __syncthreads();
            const float* W2 = mw2 + (size_t)ej * HMAX * DMODEL + tid;
            float o = mb2[ej * DMODEL + tid];
#pragma unroll 8
            for (int h = 0; h < hid; h++) o += mid[h] * W2[(size_t)h * DMODEL];
            xmlp[tid] = o;
            __syncthreads();
        }

        // ---- post: Linear (+ LN if even) ----
        {
            const float* Q = qw + (size_t)eq * DMODEL * DMODEL + tid;
            float t = qb[eq * DMODEL + tid];
#pragma unroll 8
            for (int c = 0; c < DMODEL; c++) t += xmlp[c] * Q[c * DMODEL];
            if ((eq & 1) == 0) {
                red[tid] = t; __syncthreads();
                for (int s = 128; s > 0; s >>= 1) { if (tid < s) red[tid] += red[tid + s]; __syncthreads(); }
                float mu = red[0] * (1.0f / DMODEL);
                __syncthreads();
                float dd = t - mu;
                red[tid] = dd * dd; __syncthreads();
                for (int s = 128; s > 0; s >>= 1) { if (tid < s) red[tid] += red[tid + s]; __syncthreads(); }
                float var = red[0] * (1.0f / DMODEL);
                __syncthreads();
                t = dd * rsqrtf(var + 1e-5f) * qg[eq * DMODEL + tid] + qbb[eq * DMODEL + tid];
            }
            outacc += tval * t;
            __syncthreads();   // protect xpre/mid/xmlp/red before next k
        }
    }
    out[(size_t)n * DMODEL + tid] = outacc;
}

// ---------------------------------------------------------------------------
extern "C" void kernel_launch(void* const* d_in, const int* in_sizes, int n_in,
                              void* d_out, int out_size, void* d_ws, size_t ws_size,
                              hipStream_t stream) {
    (void)in_sizes; (void)n_in; (void)out_size; (void)ws_size;

    const float* x    = (const float*)d_in[0];
    const float* rw1  = (const float*)d_in[1];
    const float* rb1  = (const float*)d_in[2];
    const float* rw2  = (const float*)d_in[3];
    const float* rb2  = (const float*)d_in[4];
    const float* rw3  = (const float*)d_in[5];
    const float* rb3  = (const float*)d_in[6];
    const float* temp = (const float*)d_in[7];
    const float* pw   = (const float*)d_in[8];
    const float* pb   = (const float*)d_in[9];
    const float* pg   = (const float*)d_in[10];
    const float* pbb  = (const float*)d_in[11];
    const float* mw1  = (const float*)d_in[12];
    const float* mb1  = (const float*)d_in[13];
    const float* mw2  = (const float*)d_in[14];
    const float* mb2  = (const float*)d_in[15];
    const float* qw   = (const float*)d_in[16];
    const float* qb   = (const float*)d_in[17];
    const float* qg   = (const float*)d_in[18];
    const float* qbb  = (const float*)d_in[19];

    float* out      = (float*)d_out;                    // [N, D]   fp32
    float* out_loss = out + (size_t)NTOK * DMODEL;      // [1]      fp32
    float* out_pw   = out_loss + 1;                     // [N, P]   fp32

    // workspace: freq partials(256KB) + top_idx(32KB) + top_val(32KB)
    float* freq_part = (float*)d_ws;
    int*   top_idx   = (int*)(freq_part + (size_t)FSLOTS * PWAYS);
    float* top_val   = (float*)(top_idx + (size_t)NTOK * TOPK);

    k_zero<<<1024, 256, 0, stream>>>(out_pw, freq_part);
    k_router_select<<<NTOK / 4, 256, 0, stream>>>(x, rw1, rb1, rw2, rb2, rw3, rb3,
                                                  temp, freq_part, top_idx, top_val, out_pw);
    k_freq_loss<<<1, 256, 0, stream>>>(freq_part, out_loss);
    k_experts<<<NTOK, 256, 0, stream>>>(x, pw, pb, pg, pbb, mw1, mb1, mw2, mb2,
                                        qw, qb, qg, qbb, top_idx, top_val, out);
}

// Round 9
// 988.552 us; speedup vs baseline: 2.5272x; 2.5272x over previous
//
#include <hip/hip_runtime.h>
#include <math.h>

#define DMODEL 256
#define PWAYS  4096
#define TOPK   4
#define HMAX   1280
#define NTOK   2048          // B*S
#define NPAIR  (NTOK*TOPK)   // 8192
#define FSLOTS 16
#define TILE   16

__device__ __forceinline__ float gelu_exact(float z) {
    return 0.5f * z * (1.0f + erff(z * 0.70710678118654752440f));
}

// ======================= shared front-end (unchanged from R8) =======================

__global__ void k_zero(float* __restrict__ pwout, float* __restrict__ freq_part) {
    const int i = blockIdx.x * 256 + threadIdx.x;
    const int stride = gridDim.x * 256;
    for (int j = i; j < NTOK * PWAYS; j += stride) pwout[j] = 0.0f;
    for (int j = i; j < FSLOTS * PWAYS; j += stride) freq_part[j] = 0.0f;
}

// zero out[] (atomic-accumulated in batched mode) + counts/offsets/cursors
__global__ void k_zero2(float* __restrict__ out, int* __restrict__ cnts) {
    const int i = blockIdx.x * 256 + threadIdx.x;
    const int stride = gridDim.x * 256;
    for (int j = i; j < NTOK * DMODEL; j += stride) out[j] = 0.0f;
    if (i < 192) cnts[i] = 0;
}

__global__ void __launch_bounds__(256) k_router_select(
    const float* __restrict__ x,
    const float* __restrict__ rw1, const float* __restrict__ rb1,
    const float* __restrict__ rw2, const float* __restrict__ rb2,
    const float* __restrict__ rw3, const float* __restrict__ rb3,
    const float* __restrict__ temp, float* __restrict__ freq_part,
    int* __restrict__ top_idx, float* __restrict__ top_vals, float* __restrict__ pw_out) {
    __shared__ float xs[4][DMODEL];
    __shared__ float h1s[4][DMODEL];
    __shared__ float h2s[4][128];
    __shared__ float red[256];
    __shared__ int redi[256];
    __shared__ int sel[TOPK];
    __shared__ float selv[TOPK];
    const int tid = threadIdx.x;
    const int n0 = blockIdx.x * 4;

    for (int idx = tid; idx < 4 * DMODEL; idx += 256)
        xs[idx >> 8][idx & 255] = x[(size_t)n0 * DMODEL + idx];
    __syncthreads();

    {
        float bias = rb1[tid];
        float a0 = bias, a1 = bias, a2 = bias, a3 = bias;
        for (int c = 0; c < DMODEL; c++) {
            float wv = rw1[c * DMODEL + tid];
            a0 += xs[0][c] * wv; a1 += xs[1][c] * wv;
            a2 += xs[2][c] * wv; a3 += xs[3][c] * wv;
        }
        h1s[0][tid] = gelu_exact(a0); h1s[1][tid] = gelu_exact(a1);
        h1s[2][tid] = gelu_exact(a2); h1s[3][tid] = gelu_exact(a3);
    }
    __syncthreads();

    {
        const int col = tid & 127;
        const int pr = tid >> 7;
        float bias = rb2[col];
        float b0 = bias, b1 = bias;
        for (int c = 0; c < DMODEL; c++) {
            float wv = rw2[c * 128 + col];
            b0 += h1s[2 * pr + 0][c] * wv;
            b1 += h1s[2 * pr + 1][c] * wv;
        }
        h2s[2 * pr + 0][col] = gelu_exact(b0);
        h2s[2 * pr + 1][col] = gelu_exact(b1);
    }
    __syncthreads();

    float sv[4][16];
#pragma unroll
    for (int i = 0; i < 16; i++) {
        float bias = rb3[tid + i * 256];
#pragma unroll
        for (int t = 0; t < 4; t++) sv[t][i] = bias;
    }
    for (int c = 0; c < 128; c++) {
        const float hv0 = h2s[0][c], hv1 = h2s[1][c], hv2 = h2s[2][c], hv3 = h2s[3][c];
        const float* wr = rw3 + (size_t)c * PWAYS + tid;
#pragma unroll
        for (int i = 0; i < 16; i++) {
            float wv = wr[i * 256];
            sv[0][i] += hv0 * wv;
            sv[1][i] += hv1 * wv;
            sv[2][i] += hv2 * wv;
            sv[3][i] += hv3 * wv;
        }
    }

    const float invT = 1.0f / temp[0];
    float psum[16];
#pragma unroll
    for (int i = 0; i < 16; i++) psum[i] = 0.0f;

    for (int t = 0; t < 4; t++) {
        const int n = n0 + t;
        float lmax = -3.402823466e38f;
#pragma unroll
        for (int i = 0; i < 16; i++) lmax = fmaxf(lmax, sv[t][i]);
        red[tid] = lmax; __syncthreads();
        for (int s = 128; s > 0; s >>= 1) {
            if (tid < s) red[tid] = fmaxf(red[tid], red[tid + s]);
            __syncthreads();
        }
        const float m = red[0];
        __syncthreads();

        float ee[16];
        float s1 = 0.f, sT = 0.f;
#pragma unroll
        for (int i = 0; i < 16; i++) {
            float d = sv[t][i] - m;
            ee[i] = expf(d);
            s1 += ee[i];
            sT += expf(d * invT);
        }
        red[tid] = s1; __syncthreads();
        for (int s = 128; s > 0; s >>= 1) { if (tid < s) red[tid] += red[tid + s]; __syncthreads(); }
        const float sum1 = red[0];
        __syncthreads();
        red[tid] = sT; __syncthreads();
        for (int s = 128; s > 0; s >>= 1) { if (tid < s) red[tid] += red[tid + s]; __syncthreads(); }
        const float sumT = red[0];
        __syncthreads();

        const float inv_s1 = 1.0f / sum1;
#pragma unroll
        for (int i = 0; i < 16; i++) psum[i] += ee[i] * inv_s1;

        for (int r = 0; r < TOPK; r++) {
            float bv = -3.402823466e38f;
            int bi = PWAYS;
#pragma unroll
            for (int i = 0; i < 16; i++) {
                int p = tid + i * 256;
                bool skip = false;
                for (int u = 0; u < r; u++) if (sel[u] == p) skip = true;
                if (!skip && sv[t][i] > bv) { bv = sv[t][i]; bi = p; }
            }
            red[tid] = bv; redi[tid] = bi; __syncthreads();
            for (int s = 128; s > 0; s >>= 1) {
                if (tid < s) {
                    if (red[tid + s] > red[tid] ||
                        (red[tid + s] == red[tid] && redi[tid + s] < redi[tid])) {
                        red[tid] = red[tid + s]; redi[tid] = redi[tid + s];
                    }
                }
                __syncthreads();
            }
            if (tid == 0) { sel[r] = redi[0]; selv[r] = red[0]; }
            __syncthreads();
        }

        if (tid == 0) {
            float tv[TOPK];
            float wsum = 1e-8f;
#pragma unroll
            for (int k2 = 0; k2 < TOPK; k2++) {
                tv[k2] = expf((selv[k2] - m) * invT) / sumT;
                wsum += tv[k2];
            }
            float invw = 1.0f / wsum;
#pragma unroll
            for (int k2 = 0; k2 < TOPK; k2++) {
                top_idx[n * TOPK + k2] = sel[k2];
                top_vals[n * TOPK + k2] = tv[k2];
                pw_out[(size_t)n * PWAYS + sel[k2]] = tv[k2] * invw;
            }
        }
        __syncthreads();
    }

    float* fp = freq_part + (size_t)(blockIdx.x & (FSLOTS - 1)) * PWAYS;
#pragma unroll
    for (int i = 0; i < 16; i++) atomicAdd(&fp[tid + i * 256], psum[i]);
}

__global__ void k_freq_loss(const float* __restrict__ freq_part, float* __restrict__ out_loss) {
    __shared__ float fl[PWAYS];
    __shared__ float red[256];
    const int tid = threadIdx.x;
    for (int p = tid; p < PWAYS; p += 256) {
        float s = 0.f;
        for (int sl = 0; sl < FSLOTS; sl++) s += freq_part[(size_t)sl * PWAYS + p];
        fl[p] = s * (1.0f / NTOK);
    }
    __syncthreads();
    float s = 0.f;
    for (int p = tid; p < PWAYS; p += 256) s += fl[p];
    red[tid] = s; __syncthreads();
    for (int st = 128; st > 0; st >>= 1) { if (tid < st) red[tid] += red[tid + st]; __syncthreads(); }
    const float mu = red[0] * (1.0f / PWAYS);
    __syncthreads();
    float ss = 0.f;
    for (int p = tid; p < PWAYS; p += 256) {
        float d = fl[p] - mu;
        ss += d * d;
    }
    red[tid] = ss; __syncthreads();
    for (int st = 128; st > 0; st >>= 1) { if (tid < st) red[tid] += red[tid + st]; __syncthreads(); }
    if (tid == 0)
        out_loss[0] = (float)PWAYS * red[0] / (float)(PWAYS - 1);
}

// ======================= expert-batched back-end =======================
// counts/offsets/cursors: [stage*16 + e], stage 0=pre 1=mlp 2=post

__global__ void k_count(const int* __restrict__ top_idx, int* __restrict__ counts) {
    const int p = blockIdx.x * 256 + threadIdx.x;
    if (p >= NPAIR) return;
    const int idx = top_idx[p];
    atomicAdd(&counts[0 * 16 + (idx >> 8)], 1);
    atomicAdd(&counts[1 * 16 + ((idx >> 4) & 15)], 1);
    atomicAdd(&counts[2 * 16 + (idx & 15)], 1);
}

__global__ void k_prefix(const int* __restrict__ counts, int* __restrict__ offsets,
                         int* __restrict__ cursors) {
    if (threadIdx.x != 0 || blockIdx.x != 0) return;
    for (int s = 0; s < 3; s++) {
        int run = 0;
        for (int e = 0; e < 16; e++) {
            offsets[s * 16 + e] = run;
            cursors[s * 16 + e] = run;
            run += counts[s * 16 + e];
        }
    }
}

__global__ void k_scatter(const int* __restrict__ top_idx, int* __restrict__ cursors,
                          int* __restrict__ lists) {
    const int p = blockIdx.x * 256 + threadIdx.x;
    if (p >= NPAIR) return;
    const int idx = top_idx[p];
    int pos;
    pos = atomicAdd(&cursors[0 * 16 + (idx >> 8)], 1);        lists[0 * NPAIR + pos] = p;
    pos = atomicAdd(&cursors[1 * 16 + ((idx >> 4) & 15)], 1); lists[1 * NPAIR + pos] = p;
    pos = atomicAdd(&cursors[2 * 16 + (idx & 15)], 1);        lists[2 * NPAIR + pos] = p;
}

__device__ __forceinline__ void wave_stats(const float* row, int lane,
                                           float& s1, float& s2) {
    float v0 = row[lane], v1 = row[lane + 64], v2 = row[lane + 128], v3 = row[lane + 192];
    s1 = v0 + v1 + v2 + v3;
    s2 = v0 * v0 + v1 * v1 + v2 * v2 + v3 * v3;
    for (int o = 32; o > 0; o >>= 1) {
        s1 += __shfl_down(s1, o);
        s2 += __shfl_down(s2, o);
    }
}

// ---- stage A: pre experts — Linear + LN + act, batched 16 pairs/block ----
__global__ void __launch_bounds__(256) k_pre(
    const float* __restrict__ x, const float* __restrict__ pw, const float* __restrict__ pb,
    const float* __restrict__ pg, const float* __restrict__ pbb,
    const int* __restrict__ counts, const int* __restrict__ offsets,
    const int* __restrict__ lists, float* __restrict__ x_pre) {
    const int e = blockIdx.x;
    const int cnt = counts[e];
    const int base = blockIdx.y * TILE;
    if (base >= cnt) return;
    const int off = offsets[e];
    const int Tact = min(TILE, cnt - base);

    __shared__ int prs[TILE];
    __shared__ float xs[TILE][DMODEL];
    __shared__ float ys[TILE][DMODEL];
    __shared__ float mus[TILE], ivs[TILE];
    const int tid = threadIdx.x;

    if (tid < TILE) prs[tid] = lists[off + base + ((tid < Tact) ? tid : (Tact - 1))];
    __syncthreads();
#pragma unroll
    for (int j = 0; j < TILE; j++)
        xs[j][tid] = x[(size_t)(prs[j] >> 2) * DMODEL + tid];
    __syncthreads();

    float acc[TILE];
    const float bias = pb[e * DMODEL + tid];
#pragma unroll
    for (int j = 0; j < TILE; j++) acc[j] = bias;
    const float* W = pw + (size_t)e * DMODEL * DMODEL + tid;
    for (int c = 0; c < DMODEL; c += 4) {
        const float w0 = W[(c + 0) * DMODEL], w1 = W[(c + 1) * DMODEL];
        const float w2 = W[(c + 2) * DMODEL], w3 = W[(c + 3) * DMODEL];
#pragma unroll
        for (int j = 0; j < TILE; j++) {
            float4 xv = *(const float4*)&xs[j][c];
            acc[j] += xv.x * w0 + xv.y * w1 + xv.z * w2 + xv.w * w3;
        }
    }
#pragma unroll
    for (int j = 0; j < TILE; j++) ys[j][tid] = acc[j];
    __syncthreads();

    const int w = tid >> 6, lane = tid & 63;
    for (int i = 0; i < 4; i++) {
        const int j = w * 4 + i;
        float s1, s2;
        wave_stats(ys[j], lane, s1, s2);
        if (lane == 0) {
            float mu = s1 * (1.0f / DMODEL);
            mus[j] = mu;
            ivs[j] = rsqrtf(s2 * (1.0f / DMODEL) - mu * mu + 1e-5f);
        }
    }
    __syncthreads();

    const float g = pg[e * DMODEL + tid], bb = pbb[e * DMODEL + tid];
    const int am = e % 3;
    for (int j = 0; j < Tact; j++) {
        float y = (acc[j] - mus[j]) * ivs[j] * g + bb;
        y = (am == 0) ? gelu_exact(y) : (am == 1 ? fmaxf(y, 0.f) : tanhf(y));
        x_pre[(size_t)prs[j] * DMODEL + tid] = y;
    }
}

// ---- stage B: mlp experts — two matmuls fused via 256-wide hidden chunks ----
__global__ void __launch_bounds__(256) k_mlp(
    const float* __restrict__ x_pre,
    const float* __restrict__ mw1, const float* __restrict__ mb1,
    const float* __restrict__ mw2, const float* __restrict__ mb2,
    const int* __restrict__ counts, const int* __restrict__ offsets,
    const int* __restrict__ lists, float* __restrict__ x_mlp) {
    const int e = blockIdx.x;
    const int cnt = counts[16 + e];
    const int base = blockIdx.y * TILE;
    if (base >= cnt) return;
    const int off = offsets[16 + e];
    const int Tact = min(TILE, cnt - base);
    const int chunks = 2 + (e >> 2);   // hid = 256*chunks

    __shared__ int prs[TILE];
    __shared__ float xs[TILE][DMODEL];
    __shared__ float midc[TILE][DMODEL];
    const int tid = threadIdx.x;

    if (tid < TILE) prs[tid] = lists[NPAIR + off + base + ((tid < Tact) ? tid : (Tact - 1))];
    __syncthreads();
#pragma unroll
    for (int j = 0; j < TILE; j++)
        xs[j][tid] = x_pre[(size_t)prs[j] * DMODEL + tid];
    __syncthreads();

    float o[TILE];
    const float ob = mb2[e * DMODEL + tid];
#pragma unroll
    for (int j = 0; j < TILE; j++) o[j] = ob;

    const bool is_gelu = ((e & 1) == 0);
    for (int ch = 0; ch < chunks; ch++) {
        const int hbase = ch * 256;
        float a[TILE];
        const float hb = mb1[e * HMAX + hbase + tid];
#pragma unroll
        for (int j = 0; j < TILE; j++) a[j] = hb;
        const float* W1 = mw1 + (size_t)e * DMODEL * HMAX + hbase + tid;
        for (int c = 0; c < DMODEL; c += 4) {
            const float w0 = W1[(size_t)(c + 0) * HMAX], w1 = W1[(size_t)(c + 1) * HMAX];
            const float w2 = W1[(size_t)(c + 2) * HMAX], w3 = W1[(size_t)(c + 3) * HMAX];
#pragma unroll
            for (int j = 0; j < TILE; j++) {
                float4 xv = *(const float4*)&xs[j][c];
                a[j] += xv.x * w0 + xv.y * w1 + xv.z * w2 + xv.w * w3;
            }
        }
        __syncthreads();   // previous chunk's midc reads complete
#pragma unroll
        for (int j = 0; j < TILE; j++)
            midc[j][tid] = is_gelu ? gelu_exact(a[j]) : fmaxf(a[j], 0.f);
        __syncthreads();

        const float* W2 = mw2 + (size_t)e * HMAX * DMODEL + (size_t)hbase * DMODEL + tid;
        for (int h = 0; h < DMODEL; h += 4) {
            const float v0 = W2[(size_t)(h + 0) * DMODEL], v1 = W2[(size_t)(h + 1) * DMODEL];
            const float v2 = W2[(size_t)(h + 2) * DMODEL], v3 = W2[(size_t)(h + 3) * DMODEL];
#pragma unroll
            for (int j = 0; j < TILE; j++) {
                float4 mv = *(const float4*)&midc[j][h];
                o[j] += mv.x * v0 + mv.y * v1 + mv.z * v2 + mv.w * v3;
            }
        }
    }
    for (int j = 0; j < Tact; j++)
        x_mlp[(size_t)prs[j] * DMODEL + tid] = o[j];
}

// ---- stage C: post experts — Linear (+LN if even), weighted atomic accumulate ----
__global__ void __launch_bounds__(256) k_post(
    const float* __restrict__ x_mlp,
    const float* __restrict__ qw, const float* __restrict__ qb,
    const float* __restrict__ qg, const float* __restrict__ qbb,
    const float* __restrict__ top_val,
    const int* __restrict__ counts, const int* __restrict__ offsets,
    const int* __restrict__ lists, float* __restrict__ out) {
    const int e = blockIdx.x;
    const int cnt = counts[32 + e];
    const int base = blockIdx.y * TILE;
    if (base >= cnt) return;
    const int off = offsets[32 + e];
    const int Tact = min(TILE, cnt - base);

    __shared__ int prs[TILE];
    __shared__ float tvs[TILE];
    __shared__ float xs[TILE][DMODEL];
    __shared__ float ys[TILE][DMODEL];
    __shared__ float mus[TILE], ivs[TILE];
    const int tid = threadIdx.x;

    if (tid < TILE) {
        int p = lists[2 * NPAIR + off + base + ((tid < Tact) ? tid : (Tact - 1))];
        prs[tid] = p;
        tvs[tid] = top_val[p];
    }
    __syncthreads();
#pragma unroll
    for (int j = 0; j < TILE; j++)
        xs[j][tid] = x_mlp[(size_t)prs[j] * DMODEL + tid];
    __syncthreads();

    float acc[TILE];
    const float bias = qb[e * DMODEL + tid];
#pragma unroll
    for (int j = 0; j < TILE; j++) acc[j] = bias;
    const float* W = qw + (size_t)e * DMODEL * DMODEL + tid;
    for (int c = 0; c < DMODEL; c += 4) {
        const float w0 = W[(c + 0) * DMODEL], w1 = W[(c + 1) * DMODEL];
        const float w2 = W[(c + 2) * DMODEL], w3 = W[(c + 3) * DMODEL];
#pragma unroll
        for (int j = 0; j < TILE; j++) {
            float4 xv = *(const float4*)&xs[j][c];
            acc[j] += xv.x * w0 + xv.y * w1 + xv.z * w2 + xv.w * w3;
        }
    }

    if ((e & 1) == 0) {
#pragma unroll
        for (int j = 0; j < TILE; j++) ys[j][tid] = acc[j];
        __syncthreads();
        const int w = tid >> 6, lane = tid & 63;
        for (int i = 0; i < 4; i++) {
            const int j = w * 4 + i;
            float s1, s2;
            wave_stats(ys[j], lane, s1, s2);
            if (lane == 0) {
                float mu = s1 * (1.0f / DMODEL);
                mus[j] = mu;
                ivs[j] = rsqrtf(s2 * (1.0f / DMODEL) - mu * mu + 1e-5f);
            }
        }
        __syncthreads();
        const float g = qg[e * DMODEL + tid], bb = qbb[e * DMODEL + tid];
        for (int j = 0; j < Tact; j++) {
            float t = (acc[j] - mus[j]) * ivs[j] * g + bb;
            atomicAdd(&out[(size_t)(prs[j] >> 2) * DMODEL + tid], tvs[j] * t);
        }
    } else {
        for (int j = 0; j < Tact; j++)
            atomicAdd(&out[(size_t)(prs[j] >> 2) * DMODEL + tid], tvs[j] * acc[j]);
    }
}

// ======================= legacy fallback (R8 k_experts) =======================
__global__ void __launch_bounds__(256) k_experts_legacy(
    const float* __restrict__ x,
    const float* __restrict__ pw, const float* __restrict__ pb,
    const float* __restrict__ pg, const float* __restrict__ pbb,
    const float* __restrict__ mw1, const float* __restrict__ mb1,
    const float* __restrict__ mw2, const float* __restrict__ mb2,
    const float* __restrict__ qw, const float* __restrict__ qb,
    const float* __restrict__ qg, const float* __restrict__ qbb,
    const int* __restrict__ top_idx, const float* __restrict__ top_vals,
    float* __restrict__ out) {
    __shared__ float xs[DMODEL];
    __shared__ float xpre[DMODEL];
    __shared__ float mid[HMAX];
    __shared__ float xmlp[DMODEL];
    __shared__ float red[256];
    const int n = blockIdx.x;
    const int tid = threadIdx.x;
    xs[tid] = x[(size_t)n * DMODEL + tid];
    __syncthreads();
    float outacc = 0.f;
    for (int k = 0; k < TOPK; k++) {
        const int idx = top_idx[n * TOPK + k];
        const float tval = top_vals[n * TOPK + k];
        const int ei = idx >> 8, ej = (idx >> 4) & 15, eq = idx & 15;
        {
            const float* W = pw + (size_t)ei * DMODEL * DMODEL + tid;
            float acc = pb[ei * DMODEL + tid];
            for (int c = 0; c < DMODEL; c++) acc += xs[c] * W[c * DMODEL];
            red[tid] = acc; __syncthreads();
            for (int s = 128; s > 0; s >>= 1) { if (tid < s) red[tid] += red[tid + s]; __syncthreads(); }
            float mu = red[0] * (1.0f / DMODEL); __syncthreads();
            float dd = acc - mu;
            red[tid] = dd * dd; __syncthreads();
            for (int s = 128; s > 0; s >>= 1) { if (tid < s) red[tid] += red[tid + s]; __syncthreads(); }
            float var = red[0] * (1.0f / DMODEL); __syncthreads();
            float y = dd * rsqrtf(var + 1e-5f) * pg[ei * DMODEL + tid] + pbb[ei * DMODEL + tid];
            const int am = ei % 3;
            y = (am == 0) ? gelu_exact(y) : (am == 1 ? fmaxf(y, 0.f) : tanhf(y));
            xpre[tid] = y; __syncthreads();
        }
        const int hid = DMODEL * (2 + (ej >> 2));
        {
            const float* W1 = mw1 + (size_t)ej * DMODEL * HMAX;
            for (int h = tid; h < hid; h += 256) {
                float a = mb1[ej * HMAX + h];
                for (int c = 0; c < DMODEL; c++) a += xpre[c] * W1[(size_t)c * HMAX + h];
                mid[h] = ((ej & 1) == 0) ? gelu_exact(a) : fmaxf(a, 0.f);
            }
            __syncthreads();
            const float* W2 = mw2 + (size_t)ej * HMAX * DMODEL + tid;
            float o = mb2[ej * DMODEL + tid];
            for (int h = 0; h < hid; h++) o += mid[h] * W2[(size_t)h * DMODEL];
            xmlp[tid] = o; __syncthreads();
        }
        {
            const float* Q = qw + (size_t)eq * DMODEL * DMODEL + tid;
            float t = qb[eq * DMODEL + tid];
            for (int c = 0; c < DMODEL; c++) t += xmlp[c] * Q[c * DMODEL];
            if ((eq & 1) == 0) {
                red[tid] = t; __syncthreads();
                for (int s = 128; s > 0; s >>= 1) { if (tid < s) red[tid] += red[tid + s]; __syncthreads(); }
                float mu = red[0] * (1.0f / DMODEL); __syncthreads();
                float dd = t - mu;
                red[tid] = dd * dd; __syncthreads();
                for (int s = 128; s > 0; s >>= 1) { if (tid < s) red[tid] += red[tid + s]; __syncthreads(); }
                float var = red[0] * (1.0f / DMODEL); __syncthreads();
                t = dd * rsqrtf(var + 1e-5f) * qg[eq * DMODEL + tid] + qbb[eq * DMODEL + tid];
            }
            outacc += tval * t;
            __syncthreads();
        }
    }
    out[(size_t)n * DMODEL + tid] = outacc;
}

// ---------------------------------------------------------------------------
extern "C" void kernel_launch(void* const* d_in, const int* in_sizes, int n_in,
                              void* d_out, int out_size, void* d_ws, size_t ws_size,
                              hipStream_t stream) {
    (void)in_sizes; (void)n_in; (void)out_size;

    const float* x    = (const float*)d_in[0];
    const float* rw1  = (const float*)d_in[1];
    const float* rb1  = (const float*)d_in[2];
    const float* rw2  = (const float*)d_in[3];
    const float* rb2  = (const float*)d_in[4];
    const float* rw3  = (const float*)d_in[5];
    const float* rb3  = (const float*)d_in[6];
    const float* temp = (const float*)d_in[7];
    const float* pw   = (const float*)d_in[8];
    const float* pb   = (const float*)d_in[9];
    const float* pg   = (const float*)d_in[10];
    const float* pbb  = (const float*)d_in[11];
    const float* mw1  = (const float*)d_in[12];
    const float* mb1  = (const float*)d_in[13];
    const float* mw2  = (const float*)d_in[14];
    const float* mb2  = (const float*)d_in[15];
    const float* qw   = (const float*)d_in[16];
    const float* qb   = (const float*)d_in[17];
    const float* qg   = (const float*)d_in[18];
    const float* qbb  = (const float*)d_in[19];

    float* out      = (float*)d_out;
    float* out_loss = out + (size_t)NTOK * DMODEL;
    float* out_pw   = out_loss + 1;

    // workspace layout
    float* freq_part = (float*)d_ws;                                  // 65536 f
    int*   top_idx   = (int*)(freq_part + (size_t)FSLOTS * PWAYS);    // 8192 i
    float* top_val   = (float*)(top_idx + NPAIR);                     // 8192 f
    int*   counts    = (int*)(top_val + NPAIR);                       // 64 i
    int*   offsets   = counts + 64;                                   // 64 i
    int*   cursors   = offsets + 64;                                  // 64 i
    int*   lists     = cursors + 64;                                  // 3*8192 i
    float* x_pre     = (float*)(lists + 3 * NPAIR);                   // 8192*256 f
    float* x_mlp     = x_pre + (size_t)NPAIR * DMODEL;                // 8192*256 f
    const size_t ws_need = (size_t)((char*)(x_mlp + (size_t)NPAIR * DMODEL) - (char*)d_ws);
    const int batched = (ws_size >= ws_need) ? 1 : 0;

    k_zero<<<1024, 256, 0, stream>>>(out_pw, freq_part);
    k_router_select<<<NTOK / 4, 256, 0, stream>>>(x, rw1, rb1, rw2, rb2, rw3, rb3,
                                                  temp, freq_part, top_idx, top_val, out_pw);
    k_freq_loss<<<1, 256, 0, stream>>>(freq_part, out_loss);

    if (batched) {
        k_zero2<<<512, 256, 0, stream>>>(out, counts);
        k_count<<<NPAIR / 256, 256, 0, stream>>>(top_idx, counts);
        k_prefix<<<1, 64, 0, stream>>>(counts, offsets, cursors);
        k_scatter<<<NPAIR / 256, 256, 0, stream>>>(top_idx, cursors, lists);
        dim3 grid(16, NPAIR / TILE);
        k_pre<<<grid, 256, 0, stream>>>(x, pw, pb, pg, pbb, counts, offsets, lists, x_pre);
        k_mlp<<<grid, 256, 0, stream>>>(x_pre, mw1, mb1, mw2, mb2, counts, offsets, lists, x_mlp);
        k_post<<<grid, 256, 0, stream>>>(x_mlp, qw, qb, qg, qbb, top_val,
                                         counts, offsets, lists, out);
    } else {
        k_experts_legacy<<<NTOK, 256, 0, stream>>>(x, pw, pb, pg, pbb, mw1, mb1, mw2, mb2,
                                                   qw, qb, qg, qbb, top_idx, top_val, out);
    }
}

// Round 10
// 837.458 us; speedup vs baseline: 2.9832x; 1.1804x over previous
//
#include <hip/hip_runtime.h>
#include <math.h>

#define DMODEL 256
#define PWAYS  4096
#define TOPK   4
#define HMAX   1280
#define NTOK   2048          // B*S
#define NPAIR  (NTOK*TOPK)   // 8192
#define FSLOTS 16
#define TILE   16
#define MLPY   64            // y-blocks for k_mlp tile loop

__device__ __forceinline__ float gelu_exact(float z) {
    return 0.5f * z * (1.0f + erff(z * 0.70710678118654752440f));
}

// ======================= shared front-end =======================

__global__ void k_zero(float* __restrict__ pwout, float* __restrict__ freq_part) {
    const int i = blockIdx.x * 256 + threadIdx.x;
    const int stride = gridDim.x * 256;
    for (int j = i; j < NTOK * PWAYS; j += stride) pwout[j] = 0.0f;
    for (int j = i; j < FSLOTS * PWAYS; j += stride) freq_part[j] = 0.0f;
}

// zero out[] + x_mlp (both atomic-accumulated) + counts
__global__ void k_zero2(float* __restrict__ out, float* __restrict__ x_mlp,
                        int* __restrict__ cnts) {
    const int i = blockIdx.x * 256 + threadIdx.x;
    const int stride = gridDim.x * 256;
    for (int j = i; j < NTOK * DMODEL; j += stride) out[j] = 0.0f;
    for (int j = i; j < NPAIR * DMODEL; j += stride) x_mlp[j] = 0.0f;
    if (i < 192) cnts[i] = 0;
}

__global__ void __launch_bounds__(256) k_router_select(
    const float* __restrict__ x,
    const float* __restrict__ rw1, const float* __restrict__ rb1,
    const float* __restrict__ rw2, const float* __restrict__ rb2,
    const float* __restrict__ rw3, const float* __restrict__ rb3,
    const float* __restrict__ temp, float* __restrict__ freq_part,
    int* __restrict__ top_idx, float* __restrict__ top_vals, float* __restrict__ pw_out) {
    __shared__ float xs[4][DMODEL];
    __shared__ float h1s[4][DMODEL];
    __shared__ float h2s[4][128];
    __shared__ float red[256];
    __shared__ int redi[256];
    __shared__ int sel[TOPK];
    __shared__ float selv[TOPK];
    const int tid = threadIdx.x;
    const int n0 = blockIdx.x * 4;

    for (int idx = tid; idx < 4 * DMODEL; idx += 256)
        xs[idx >> 8][idx & 255] = x[(size_t)n0 * DMODEL + idx];
    __syncthreads();

    {
        float bias = rb1[tid];
        float a0 = bias, a1 = bias, a2 = bias, a3 = bias;
        for (int c = 0; c < DMODEL; c++) {
            float wv = rw1[c * DMODEL + tid];
            a0 += xs[0][c] * wv; a1 += xs[1][c] * wv;
            a2 += xs[2][c] * wv; a3 += xs[3][c] * wv;
        }
        h1s[0][tid] = gelu_exact(a0); h1s[1][tid] = gelu_exact(a1);
        h1s[2][tid] = gelu_exact(a2); h1s[3][tid] = gelu_exact(a3);
    }
    __syncthreads();

    {
        const int col = tid & 127;
        const int pr = tid >> 7;
        float bias = rb2[col];
        float b0 = bias, b1 = bias;
        for (int c = 0; c < DMODEL; c++) {
            float wv = rw2[c * 128 + col];
            b0 += h1s[2 * pr + 0][c] * wv;
            b1 += h1s[2 * pr + 1][c] * wv;
        }
        h2s[2 * pr + 0][col] = gelu_exact(b0);
        h2s[2 * pr + 1][col] = gelu_exact(b1);
    }
    __syncthreads();

    float sv[4][16];
#pragma unroll
    for (int i = 0; i < 16; i++) {
        float bias = rb3[tid + i * 256];
#pragma unroll
        for (int t = 0; t < 4; t++) sv[t][i] = bias;
    }
    for (int c = 0; c < 128; c++) {
        const float hv0 = h2s[0][c], hv1 = h2s[1][c], hv2 = h2s[2][c], hv3 = h2s[3][c];
        const float* wr = rw3 + (size_t)c * PWAYS + tid;
#pragma unroll
        for (int i = 0; i < 16; i++) {
            float wv = wr[i * 256];
            sv[0][i] += hv0 * wv;
            sv[1][i] += hv1 * wv;
            sv[2][i] += hv2 * wv;
            sv[3][i] += hv3 * wv;
        }
    }

    const float invT = 1.0f / temp[0];
    float psum[16];
#pragma unroll
    for (int i = 0; i < 16; i++) psum[i] = 0.0f;

    for (int t = 0; t < 4; t++) {
        const int n = n0 + t;
        float lmax = -3.402823466e38f;
#pragma unroll
        for (int i = 0; i < 16; i++) lmax = fmaxf(lmax, sv[t][i]);
        red[tid] = lmax; __syncthreads();
        for (int s = 128; s > 0; s >>= 1) {
            if (tid < s) red[tid] = fmaxf(red[tid], red[tid + s]);
            __syncthreads();
        }
        const float m = red[0];
        __syncthreads();

        float ee[16];
        float s1 = 0.f, sT = 0.f;
#pragma unroll
        for (int i = 0; i < 16; i++) {
            float d = sv[t][i] - m;
            ee[i] = expf(d);
            s1 += ee[i];
            sT += expf(d * invT);
        }
        red[tid] = s1; __syncthreads();
        for (int s = 128; s > 0; s >>= 1) { if (tid < s) red[tid] += red[tid + s]; __syncthreads(); }
        const float sum1 = red[0];
        __syncthreads();
        red[tid] = sT; __syncthreads();
        for (int s = 128; s > 0; s >>= 1) { if (tid < s) red[tid] += red[tid + s]; __syncthreads(); }
        const float sumT = red[0];
        __syncthreads();

        const float inv_s1 = 1.0f / sum1;
#pragma unroll
        for (int i = 0; i < 16; i++) psum[i] += ee[i] * inv_s1;

        for (int r = 0; r < TOPK; r++) {
            float bv = -3.402823466e38f;
            int bi = PWAYS;
#pragma unroll
            for (int i = 0; i < 16; i++) {
                int p = tid + i * 256;
                bool skip = false;
                for (int u = 0; u < r; u++) if (sel[u] == p) skip = true;
                if (!skip && sv[t][i] > bv) { bv = sv[t][i]; bi = p; }
            }
            red[tid] = bv; redi[tid] = bi; __syncthreads();
            for (int s = 128; s > 0; s >>= 1) {
                if (tid < s) {
                    if (red[tid + s] > red[tid] ||
                        (red[tid + s] == red[tid] && redi[tid + s] < redi[tid])) {
                        red[tid] = red[tid + s]; redi[tid] = redi[tid + s];
                    }
                }
                __syncthreads();
            }
            if (tid == 0) { sel[r] = redi[0]; selv[r] = red[0]; }
            __syncthreads();
        }

        if (tid == 0) {
            float tv[TOPK];
            float wsum = 1e-8f;
#pragma unroll
            for (int k2 = 0; k2 < TOPK; k2++) {
                tv[k2] = expf((selv[k2] - m) * invT) / sumT;
                wsum += tv[k2];
            }
            float invw = 1.0f / wsum;
#pragma unroll
            for (int k2 = 0; k2 < TOPK; k2++) {
                top_idx[n * TOPK + k2] = sel[k2];
                top_vals[n * TOPK + k2] = tv[k2];
                pw_out[(size_t)n * PWAYS + sel[k2]] = tv[k2] * invw;
            }
        }
        __syncthreads();
    }

    float* fp = freq_part + (size_t)(blockIdx.x & (FSLOTS - 1)) * PWAYS;
#pragma unroll
    for (int i = 0; i < 16; i++) atomicAdd(&fp[tid + i * 256], psum[i]);
}

__global__ void k_freq_loss(const float* __restrict__ freq_part, float* __restrict__ out_loss) {
    __shared__ float fl[PWAYS];
    __shared__ float red[256];
    const int tid = threadIdx.x;
    for (int p = tid; p < PWAYS; p += 256) {
        float s = 0.f;
        for (int sl = 0; sl < FSLOTS; sl++) s += freq_part[(size_t)sl * PWAYS + p];
        fl[p] = s * (1.0f / NTOK);
    }
    __syncthreads();
    float s = 0.f;
    for (int p = tid; p < PWAYS; p += 256) s += fl[p];
    red[tid] = s; __syncthreads();
    for (int st = 128; st > 0; st >>= 1) { if (tid < st) red[tid] += red[tid + st]; __syncthreads(); }
    const float mu = red[0] * (1.0f / PWAYS);
    __syncthreads();
    float ss = 0.f;
    for (int p = tid; p < PWAYS; p += 256) {
        float d = fl[p] - mu;
        ss += d * d;
    }
    red[tid] = ss; __syncthreads();
    for (int st = 128; st > 0; st >>= 1) { if (tid < st) red[tid] += red[tid + st]; __syncthreads(); }
    if (tid == 0)
        out_loss[0] = (float)PWAYS * red[0] / (float)(PWAYS - 1);
}

// ======================= expert-batched back-end =======================

__global__ void k_count(const int* __restrict__ top_idx, int* __restrict__ counts) {
    const int p = blockIdx.x * 256 + threadIdx.x;
    if (p >= NPAIR) return;
    const int idx = top_idx[p];
    atomicAdd(&counts[0 * 16 + (idx >> 8)], 1);
    atomicAdd(&counts[1 * 16 + ((idx >> 4) & 15)], 1);
    atomicAdd(&counts[2 * 16 + (idx & 15)], 1);
}

__global__ void k_prefix(const int* __restrict__ counts, int* __restrict__ offsets,
                         int* __restrict__ cursors) {
    if (threadIdx.x != 0 || blockIdx.x != 0) return;
    for (int s = 0; s < 3; s++) {
        int run = 0;
        for (int e = 0; e < 16; e++) {
            offsets[s * 16 + e] = run;
            cursors[s * 16 + e] = run;
            run += counts[s * 16 + e];
        }
    }
}

__global__ void k_scatter(const int* __restrict__ top_idx, int* __restrict__ cursors,
                          int* __restrict__ lists) {
    const int p = blockIdx.x * 256 + threadIdx.x;
    if (p >= NPAIR) return;
    const int idx = top_idx[p];
    int pos;
    pos = atomicAdd(&cursors[0 * 16 + (idx >> 8)], 1);        lists[0 * NPAIR + pos] = p;
    pos = atomicAdd(&cursors[1 * 16 + ((idx >> 4) & 15)], 1); lists[1 * NPAIR + pos] = p;
    pos = atomicAdd(&cursors[2 * 16 + (idx & 15)], 1);        lists[2 * NPAIR + pos] = p;
}

__device__ __forceinline__ void wave_stats(const float* row, int lane,
                                           float& s1, float& s2) {
    float v0 = row[lane], v1 = row[lane + 64], v2 = row[lane + 128], v3 = row[lane + 192];
    s1 = v0 + v1 + v2 + v3;
    s2 = v0 * v0 + v1 * v1 + v2 * v2 + v3 * v3;
    for (int o = 32; o > 0; o >>= 1) {
        s1 += __shfl_down(s1, o);
        s2 += __shfl_down(s2, o);
    }
}

// ---- stage A: pre experts — Linear + LN + act, batched 16 pairs/block ----
__global__ void __launch_bounds__(256) k_pre(
    const float* __restrict__ x, const float* __restrict__ pw, const float* __restrict__ pb,
    const float* __restrict__ pg, const float* __restrict__ pbb,
    const int* __restrict__ counts, const int* __restrict__ offsets,
    const int* __restrict__ lists, float* __restrict__ x_pre) {
    const int e = blockIdx.x;
    const int cnt = counts[e];
    const int base = blockIdx.y * TILE;
    if (base >= cnt) return;
    const int off = offsets[e];
    const int Tact = min(TILE, cnt - base);

    __shared__ int prs[TILE];
    __shared__ float xs[TILE][DMODEL];
    __shared__ float ys[TILE][DMODEL];
    __shared__ float mus[TILE], ivs[TILE];
    const int tid = threadIdx.x;

    if (tid < TILE) prs[tid] = lists[off + base + ((tid < Tact) ? tid : (Tact - 1))];
    __syncthreads();
#pragma unroll
    for (int j = 0; j < TILE; j++)
        xs[j][tid] = x[(size_t)(prs[j] >> 2) * DMODEL + tid];
    __syncthreads();

    float acc[TILE];
    const float bias = pb[e * DMODEL + tid];
#pragma unroll
    for (int j = 0; j < TILE; j++) acc[j] = bias;
    const float* W = pw + (size_t)e * DMODEL * DMODEL + tid;
    for (int c = 0; c < DMODEL; c += 4) {
        const float w0 = W[(c + 0) * DMODEL], w1 = W[(c + 1) * DMODEL];
        const float w2 = W[(c + 2) * DMODEL], w3 = W[(c + 3) * DMODEL];
#pragma unroll
        for (int j = 0; j < TILE; j++) {
            float4 xv = *(const float4*)&xs[j][c];
            acc[j] += xv.x * w0 + xv.y * w1 + xv.z * w2 + xv.w * w3;
        }
    }
#pragma unroll
    for (int j = 0; j < TILE; j++) ys[j][tid] = acc[j];
    __syncthreads();

    const int w = tid >> 6, lane = tid & 63;
    for (int i = 0; i < 4; i++) {
        const int j = w * 4 + i;
        float s1, s2;
        wave_stats(ys[j], lane, s1, s2);
        if (lane == 0) {
            float mu = s1 * (1.0f / DMODEL);
            mus[j] = mu;
            ivs[j] = rsqrtf(s2 * (1.0f / DMODEL) - mu * mu + 1e-5f);
        }
    }
    __syncthreads();

    const float g = pg[e * DMODEL + tid], bb = pbb[e * DMODEL + tid];
    const int am = e % 3;
    for (int j = 0; j < Tact; j++) {
        float y = (acc[j] - mus[j]) * ivs[j] * g + bb;
        y = (am == 0) ? gelu_exact(y) : (am == 1 ? fmaxf(y, 0.f) : tanhf(y));
        x_pre[(size_t)prs[j] * DMODEL + tid] = y;
    }
}

// ---- stage B: mlp experts — chunk-parallel: one block = (expert, tile, hidden-chunk) ----
// partial matmul2 results atomicAdd'ed into zero-initialized x_mlp; chunk 0 adds bias.
__global__ void __launch_bounds__(256) k_mlp(
    const float* __restrict__ x_pre,
    const float* __restrict__ mw1, const float* __restrict__ mb1,
    const float* __restrict__ mw2, const float* __restrict__ mb2,
    const int* __restrict__ counts, const int* __restrict__ offsets,
    const int* __restrict__ lists, float* __restrict__ x_mlp) {
    const int e = blockIdx.x;
    const int ch = blockIdx.z;
    const int chunks = 2 + (e >> 2);       // hid = 256*chunks
    if (ch >= chunks) return;
    const int cnt = counts[16 + e];
    const int off = offsets[16 + e];
    const int hbase = ch * 256;
    const bool is_gelu = ((e & 1) == 0);
    const int tid = threadIdx.x;

    __shared__ int prs[TILE];
    __shared__ float xs[TILE][DMODEL];
    __shared__ float midc[TILE][DMODEL];

    for (int base = blockIdx.y * TILE; base < cnt; base += MLPY * TILE) {
        const int Tact = min(TILE, cnt - base);

        if (tid < TILE) prs[tid] = lists[NPAIR + off + base + ((tid < Tact) ? tid : (Tact - 1))];
        __syncthreads();
#pragma unroll
        for (int j = 0; j < TILE; j++)
            xs[j][tid] = x_pre[(size_t)prs[j] * DMODEL + tid];
        __syncthreads();

        // matmul1: this chunk's 256 hidden cols
        float a[TILE];
        const float hb = mb1[e * HMAX + hbase + tid];
#pragma unroll
        for (int j = 0; j < TILE; j++) a[j] = hb;
        const float* W1 = mw1 + (size_t)e * DMODEL * HMAX + hbase + tid;
        for (int c = 0; c < DMODEL; c += 4) {
            const float w0 = W1[(size_t)(c + 0) * HMAX], w1 = W1[(size_t)(c + 1) * HMAX];
            const float w2 = W1[(size_t)(c + 2) * HMAX], w3 = W1[(size_t)(c + 3) * HMAX];
#pragma unroll
            for (int j = 0; j < TILE; j++) {
                float4 xv = *(const float4*)&xs[j][c];
                a[j] += xv.x * w0 + xv.y * w1 + xv.z * w2 + xv.w * w3;
            }
        }
#pragma unroll
        for (int j = 0; j < TILE; j++)
            midc[j][tid] = is_gelu ? gelu_exact(a[j]) : fmaxf(a[j], 0.f);
        __syncthreads();

        // matmul2 partial: this chunk's contribution to all 256 output cols
        float o[TILE];
        const float ob = (ch == 0) ? mb2[e * DMODEL + tid] : 0.0f;
#pragma unroll
        for (int j = 0; j < TILE; j++) o[j] = ob;
        const float* W2 = mw2 + (size_t)e * HMAX * DMODEL + (size_t)hbase * DMODEL + tid;
        for (int h = 0; h < DMODEL; h += 4) {
            const float v0 = W2[(size_t)(h + 0) * DMODEL], v1 = W2[(size_t)(h + 1) * DMODEL];
            const float v2 = W2[(size_t)(h + 2) * DMODEL], v3 = W2[(size_t)(h + 3) * DMODEL];
#pragma unroll
            for (int j = 0; j < TILE; j++) {
                float4 mv = *(const float4*)&midc[j][h];
                o[j] += mv.x * v0 + mv.y * v1 + mv.z * v2 + mv.w * v3;
            }
        }
        for (int j = 0; j < Tact; j++)
            atomicAdd(&x_mlp[(size_t)prs[j] * DMODEL + tid], o[j]);
        __syncthreads();   // protect prs/xs/midc before next tile iteration
    }
}

// ---- stage C: post experts — Linear (+LN if even), weighted atomic accumulate ----
__global__ void __launch_bounds__(256) k_post(
    const float* __restrict__ x_mlp,
    const float* __restrict__ qw, const float* __restrict__ qb,
    const float* __restrict__ qg, const float* __restrict__ qbb,
    const float* __restrict__ top_val,
    const int* __restrict__ counts, const int* __restrict__ offsets,
    const int* __restrict__ lists, float* __restrict__ out) {
    const int e = blockIdx.x;
    const int cnt = counts[32 + e];
    const int base = blockIdx.y * TILE;
    if (base >= cnt) return;
    const int off = offsets[32 + e];
    const int Tact = min(TILE, cnt - base);

    __shared__ int prs[TILE];
    __shared__ float tvs[TILE];
    __shared__ float xs[TILE][DMODEL];
    __shared__ float ys[TILE][DMODEL];
    __shared__ float mus[TILE], ivs[TILE];
    const int tid = threadIdx.x;

    if (tid < TILE) {
        int p = lists[2 * NPAIR + off + base + ((tid < Tact) ? tid : (Tact - 1))];
        prs[tid] = p;
        tvs[tid] = top_val[p];
    }
    __syncthreads();
#pragma unroll
    for (int j = 0; j < TILE; j++)
        xs[j][tid] = x_mlp[(size_t)prs[j] * DMODEL + tid];
    __syncthreads();

    float acc[TILE];
    const float bias = qb[e * DMODEL + tid];
#pragma unroll
    for (int j = 0; j < TILE; j++) acc[j] = bias;
    const float* W = qw + (size_t)e * DMODEL * DMODEL + tid;
    for (int c = 0; c < DMODEL; c += 4) {
        const float w0 = W[(c + 0) * DMODEL], w1 = W[(c + 1) * DMODEL];
        const float w2 = W[(c + 2) * DMODEL], w3 = W[(c + 3) * DMODEL];
#pragma unroll
        for (int j = 0; j < TILE; j++) {
            float4 xv = *(const float4*)&xs[j][c];
            acc[j] += xv.x * w0 + xv.y * w1 + xv.z * w2 + xv.w * w3;
        }
    }

    if ((e & 1) == 0) {
#pragma unroll
        for (int j = 0; j < TILE; j++) ys[j][tid] = acc[j];
        __syncthreads();
        const int w = tid >> 6, lane = tid & 63;
        for (int i = 0; i < 4; i++) {
            const int j = w * 4 + i;
            float s1, s2;
            wave_stats(ys[j], lane, s1, s2);
            if (lane == 0) {
                float mu = s1 * (1.0f / DMODEL);
                mus[j] = mu;
                ivs[j] = rsqrtf(s2 * (1.0f / DMODEL) - mu * mu + 1e-5f);
            }
        }
        __syncthreads();
        const float g = qg[e * DMODEL + tid], bb = qbb[e * DMODEL + tid];
        for (int j = 0; j < Tact; j++) {
            float t = (acc[j] - mus[j]) * ivs[j] * g + bb;
            atomicAdd(&out[(size_t)(prs[j] >> 2) * DMODEL + tid], tvs[j] * t);
        }
    } else {
        for (int j = 0; j < Tact; j++)
            atomicAdd(&out[(size_t)(prs[j] >> 2) * DMODEL + tid], tvs[j] * acc[j]);
    }
}

// ---------------------------------------------------------------------------
extern "C" void kernel_launch(void* const* d_in, const int* in_sizes, int n_in,
                              void* d_out, int out_size, void* d_ws, size_t ws_size,
                              hipStream_t stream) {
    (void)in_sizes; (void)n_in; (void)out_size; (void)ws_size;

    const float* x    = (const float*)d_in[0];
    const float* rw1  = (const float*)d_in[1];
    const float* rb1  = (const float*)d_in[2];
    const float* rw2  = (const float*)d_in[3];
    const float* rb2  = (const float*)d_in[4];
    const float* rw3  = (const float*)d_in[5];
    const float* rb3  = (const float*)d_in[6];
    const float* temp = (const float*)d_in[7];
    const float* pw   = (const float*)d_in[8];
    const float* pb   = (const float*)d_in[9];
    const float* pg   = (const float*)d_in[10];
    const float* pbb  = (const float*)d_in[11];
    const float* mw1  = (const float*)d_in[12];
    const float* mb1  = (const float*)d_in[13];
    const float* mw2  = (const float*)d_in[14];
    const float* mb2  = (const float*)d_in[15];
    const float* qw   = (const float*)d_in[16];
    const float* qb   = (const float*)d_in[17];
    const float* qg   = (const float*)d_in[18];
    const float* qbb  = (const float*)d_in[19];

    float* out      = (float*)d_out;
    float* out_loss = out + (size_t)NTOK * DMODEL;
    float* out_pw   = out_loss + 1;

    float* freq_part = (float*)d_ws;                                  // 65536 f
    int*   top_idx   = (int*)(freq_part + (size_t)FSLOTS * PWAYS);    // 8192 i
    float* top_val   = (float*)(top_idx + NPAIR);                     // 8192 f
    int*   counts    = (int*)(top_val + NPAIR);                       // 64 i
    int*   offsets   = counts + 64;                                   // 64 i
    int*   cursors   = offsets + 64;                                  // 64 i
    int*   lists     = cursors + 64;                                  // 3*8192 i
    float* x_pre     = (float*)(lists + 3 * NPAIR);                   // 8192*256 f
    float* x_mlp     = x_pre + (size_t)NPAIR * DMODEL;                // 8192*256 f

    k_zero<<<1024, 256, 0, stream>>>(out_pw, freq_part);
    k_router_select<<<NTOK / 4, 256, 0, stream>>>(x, rw1, rb1, rw2, rb2, rw3, rb3,
                                                  temp, freq_part, top_idx, top_val, out_pw);
    k_freq_loss<<<1, 256, 0, stream>>>(freq_part, out_loss);

    k_zero2<<<1024, 256, 0, stream>>>(out, x_mlp, counts);
    k_count<<<NPAIR / 256, 256, 0, stream>>>(top_idx, counts);
    k_prefix<<<1, 64, 0, stream>>>(counts, offsets, cursors);
    k_scatter<<<NPAIR / 256, 256, 0, stream>>>(top_idx, cursors, lists);
    k_pre<<<dim3(16, NPAIR / TILE), 256, 0, stream>>>(x, pw, pb, pg, pbb,
                                                      counts, offsets, lists, x_pre);
    k_mlp<<<dim3(16, MLPY, 5), 256, 0, stream>>>(x_pre, mw1, mb1, mw2, mb2,
                                                 counts, offsets, lists, x_mlp);
    k_post<<<dim3(16, NPAIR / TILE), 256, 0, stream>>>(x_mlp, qw, qb, qg, qbb, top_val,
                                                       counts, offsets, lists, out);
}

// Round 11
// 802.160 us; speedup vs baseline: 3.1145x; 1.0440x over previous
//
#include <hip/hip_runtime.h>
#include <math.h>

#define DMODEL 256
#define PWAYS  4096
#define TOPK   4
#define HMAX   1280
#define NTOK   2048          // B*S
#define NPAIR  (NTOK*TOPK)   // 8192
#define FSLOTS 16
#define TILE   16
#define YBLK   64            // y-blocks for expert-stage tile loops

__device__ __forceinline__ float gelu_exact(float z) {
    return 0.5f * z * (1.0f + erff(z * 0.70710678118654752440f));
}

// ======================= shared front-end =======================

__global__ void k_zero(float* __restrict__ pwout, float* __restrict__ freq_part) {
    const int i = blockIdx.x * 256 + threadIdx.x;
    const int stride = gridDim.x * 256;
    for (int j = i; j < NTOK * PWAYS; j += stride) pwout[j] = 0.0f;
    for (int j = i; j < FSLOTS * PWAYS; j += stride) freq_part[j] = 0.0f;
}

// zero out[] + x_mlp (both atomic-accumulated) + counts
__global__ void k_zero2(float* __restrict__ out, float* __restrict__ x_mlp,
                        int* __restrict__ cnts) {
    const int i = blockIdx.x * 256 + threadIdx.x;
    const int stride = gridDim.x * 256;
    for (int j = i; j < NTOK * DMODEL; j += stride) out[j] = 0.0f;
    for (int j = i; j < NPAIR * DMODEL; j += stride) x_mlp[j] = 0.0f;
    if (i < 192) cnts[i] = 0;
}

__global__ void __launch_bounds__(256) k_router_select(
    const float* __restrict__ x,
    const float* __restrict__ rw1, const float* __restrict__ rb1,
    const float* __restrict__ rw2, const float* __restrict__ rb2,
    const float* __restrict__ rw3, const float* __restrict__ rb3,
    const float* __restrict__ temp, float* __restrict__ freq_part,
    int* __restrict__ top_idx, float* __restrict__ top_vals, float* __restrict__ pw_out) {
    __shared__ float xs[4][DMODEL];
    __shared__ float h1s[4][DMODEL];
    __shared__ float h2s[4][128];
    __shared__ float red[256];
    __shared__ int redi[256];
    __shared__ int sel[TOPK];
    __shared__ float selv[TOPK];
    const int tid = threadIdx.x;
    const int n0 = blockIdx.x * 4;

    for (int idx = tid; idx < 4 * DMODEL; idx += 256)
        xs[idx >> 8][idx & 255] = x[(size_t)n0 * DMODEL + idx];
    __syncthreads();

    {
        float bias = rb1[tid];
        float a0 = bias, a1 = bias, a2 = bias, a3 = bias;
        for (int c = 0; c < DMODEL; c++) {
            float wv = rw1[c * DMODEL + tid];
            a0 += xs[0][c] * wv; a1 += xs[1][c] * wv;
            a2 += xs[2][c] * wv; a3 += xs[3][c] * wv;
        }
        h1s[0][tid] = gelu_exact(a0); h1s[1][tid] = gelu_exact(a1);
        h1s[2][tid] = gelu_exact(a2); h1s[3][tid] = gelu_exact(a3);
    }
    __syncthreads();

    {
        const int col = tid & 127;
        const int pr = tid >> 7;
        float bias = rb2[col];
        float b0 = bias, b1 = bias;
        for (int c = 0; c < DMODEL; c++) {
            float wv = rw2[c * 128 + col];
            b0 += h1s[2 * pr + 0][c] * wv;
            b1 += h1s[2 * pr + 1][c] * wv;
        }
        h2s[2 * pr + 0][col] = gelu_exact(b0);
        h2s[2 * pr + 1][col] = gelu_exact(b1);
    }
    __syncthreads();

    float sv[4][16];
#pragma unroll
    for (int i = 0; i < 16; i++) {
        float bias = rb3[tid + i * 256];
#pragma unroll
        for (int t = 0; t < 4; t++) sv[t][i] = bias;
    }
    for (int c = 0; c < 128; c++) {
        const float hv0 = h2s[0][c], hv1 = h2s[1][c], hv2 = h2s[2][c], hv3 = h2s[3][c];
        const float* wr = rw3 + (size_t)c * PWAYS + tid;
#pragma unroll
        for (int i = 0; i < 16; i++) {
            float wv = wr[i * 256];
            sv[0][i] += hv0 * wv;
            sv[1][i] += hv1 * wv;
            sv[2][i] += hv2 * wv;
            sv[3][i] += hv3 * wv;
        }
    }

    const float invT = 1.0f / temp[0];
    float psum[16];
#pragma unroll
    for (int i = 0; i < 16; i++) psum[i] = 0.0f;

    for (int t = 0; t < 4; t++) {
        const int n = n0 + t;
        float lmax = -3.402823466e38f;
#pragma unroll
        for (int i = 0; i < 16; i++) lmax = fmaxf(lmax, sv[t][i]);
        red[tid] = lmax; __syncthreads();
        for (int s = 128; s > 0; s >>= 1) {
            if (tid < s) red[tid] = fmaxf(red[tid], red[tid + s]);
            __syncthreads();
        }
        const float m = red[0];
        __syncthreads();

        float ee[16];
        float s1 = 0.f, sT = 0.f;
#pragma unroll
        for (int i = 0; i < 16; i++) {
            float d = sv[t][i] - m;
            ee[i] = expf(d);
            s1 += ee[i];
            sT += expf(d * invT);
        }
        red[tid] = s1; __syncthreads();
        for (int s = 128; s > 0; s >>= 1) { if (tid < s) red[tid] += red[tid + s]; __syncthreads(); }
        const float sum1 = red[0];
        __syncthreads();
        red[tid] = sT; __syncthreads();
        for (int s = 128; s > 0; s >>= 1) { if (tid < s) red[tid] += red[tid + s]; __syncthreads(); }
        const float sumT = red[0];
        __syncthreads();

        const float inv_s1 = 1.0f / sum1;
#pragma unroll
        for (int i = 0; i < 16; i++) psum[i] += ee[i] * inv_s1;

        for (int r = 0; r < TOPK; r++) {
            float bv = -3.402823466e38f;
            int bi = PWAYS;
#pragma unroll
            for (int i = 0; i < 16; i++) {
                int p = tid + i * 256;
                bool skip = false;
                for (int u = 0; u < r; u++) if (sel[u] == p) skip = true;
                if (!skip && sv[t][i] > bv) { bv = sv[t][i]; bi = p; }
            }
            red[tid] = bv; redi[tid] = bi; __syncthreads();
            for (int s = 128; s > 0; s >>= 1) {
                if (tid < s) {
                    if (red[tid + s] > red[tid] ||
                        (red[tid + s] == red[tid] && redi[tid + s] < redi[tid])) {
                        red[tid] = red[tid + s]; redi[tid] = redi[tid + s];
                    }
                }
                __syncthreads();
            }
            if (tid == 0) { sel[r] = redi[0]; selv[r] = red[0]; }
            __syncthreads();
        }

        if (tid == 0) {
            float tv[TOPK];
            float wsum = 1e-8f;
#pragma unroll
            for (int k2 = 0; k2 < TOPK; k2++) {
                tv[k2] = expf((selv[k2] - m) * invT) / sumT;
                wsum += tv[k2];
            }
            float invw = 1.0f / wsum;
#pragma unroll
            for (int k2 = 0; k2 < TOPK; k2++) {
                top_idx[n * TOPK + k2] = sel[k2];
                top_vals[n * TOPK + k2] = tv[k2];
                pw_out[(size_t)n * PWAYS + sel[k2]] = tv[k2] * invw;
            }
        }
        __syncthreads();
    }

    float* fp = freq_part + (size_t)(blockIdx.x & (FSLOTS - 1)) * PWAYS;
#pragma unroll
    for (int i = 0; i < 16; i++) atomicAdd(&fp[tid + i * 256], psum[i]);
}

__global__ void k_freq_loss(const float* __restrict__ freq_part, float* __restrict__ out_loss) {
    __shared__ float fl[PWAYS];
    __shared__ float red[256];
    const int tid = threadIdx.x;
    for (int p = tid; p < PWAYS; p += 256) {
        float s = 0.f;
        for (int sl = 0; sl < FSLOTS; sl++) s += freq_part[(size_t)sl * PWAYS + p];
        fl[p] = s * (1.0f / NTOK);
    }
    __syncthreads();
    float s = 0.f;
    for (int p = tid; p < PWAYS; p += 256) s += fl[p];
    red[tid] = s; __syncthreads();
    for (int st = 128; st > 0; st >>= 1) { if (tid < st) red[tid] += red[tid + st]; __syncthreads(); }
    const float mu = red[0] * (1.0f / PWAYS);
    __syncthreads();
    float ss = 0.f;
    for (int p = tid; p < PWAYS; p += 256) {
        float d = fl[p] - mu;
        ss += d * d;
    }
    red[tid] = ss; __syncthreads();
    for (int st = 128; st > 0; st >>= 1) { if (tid < st) red[tid] += red[tid + st]; __syncthreads(); }
    if (tid == 0)
        out_loss[0] = (float)PWAYS * red[0] / (float)(PWAYS - 1);
}

// ======================= expert-batched back-end =======================

__global__ void k_count(const int* __restrict__ top_idx, int* __restrict__ counts) {
    const int p = blockIdx.x * 256 + threadIdx.x;
    if (p >= NPAIR) return;
    const int idx = top_idx[p];
    atomicAdd(&counts[0 * 16 + (idx >> 8)], 1);
    atomicAdd(&counts[1 * 16 + ((idx >> 4) & 15)], 1);
    atomicAdd(&counts[2 * 16 + (idx & 15)], 1);
}

__global__ void k_prefix(const int* __restrict__ counts, int* __restrict__ offsets,
                         int* __restrict__ cursors) {
    if (threadIdx.x != 0 || blockIdx.x != 0) return;
    for (int s = 0; s < 3; s++) {
        int run = 0;
        for (int e = 0; e < 16; e++) {
            offsets[s * 16 + e] = run;
            cursors[s * 16 + e] = run;
            run += counts[s * 16 + e];
        }
    }
}

__global__ void k_scatter(const int* __restrict__ top_idx, int* __restrict__ cursors,
                          int* __restrict__ lists) {
    const int p = blockIdx.x * 256 + threadIdx.x;
    if (p >= NPAIR) return;
    const int idx = top_idx[p];
    int pos;
    pos = atomicAdd(&cursors[0 * 16 + (idx >> 8)], 1);        lists[0 * NPAIR + pos] = p;
    pos = atomicAdd(&cursors[1 * 16 + ((idx >> 4) & 15)], 1); lists[1 * NPAIR + pos] = p;
    pos = atomicAdd(&cursors[2 * 16 + (idx & 15)], 1);        lists[2 * NPAIR + pos] = p;
}

__device__ __forceinline__ void wave_stats(const float* row, int lane,
                                           float& s1, float& s2) {
    float v0 = row[lane], v1 = row[lane + 64], v2 = row[lane + 128], v3 = row[lane + 192];
    s1 = v0 + v1 + v2 + v3;
    s2 = v0 * v0 + v1 * v1 + v2 * v2 + v3 * v3;
    for (int o = 32; o > 0; o >>= 1) {
        s1 += __shfl_down(s1, o);
        s2 += __shfl_down(s2, o);
    }
}

// ---- stage A: pre experts — Linear + LN + act; single 16KB LDS buffer (overlay) ----
__global__ void __launch_bounds__(256, 8) k_pre(
    const float* __restrict__ x, const float* __restrict__ pw, const float* __restrict__ pb,
    const float* __restrict__ pg, const float* __restrict__ pbb,
    const int* __restrict__ counts, const int* __restrict__ offsets,
    const int* __restrict__ lists, float* __restrict__ x_pre) {
    const int e = blockIdx.x;
    const int cnt = counts[e];
    const int off = offsets[e];
    const int tid = threadIdx.x;
    const float bias = pb[e * DMODEL + tid];
    const float g = pg[e * DMODEL + tid], bb = pbb[e * DMODEL + tid];
    const int am = e % 3;
    const float* W = pw + (size_t)e * DMODEL * DMODEL + tid;

    __shared__ int prs[TILE];
    __shared__ float buf[TILE][DMODEL];   // x-stage, then acc (overlaid)
    __shared__ float mus[TILE], ivs[TILE];

    for (int base = blockIdx.y * TILE; base < cnt; base += YBLK * TILE) {
        const int Tact = min(TILE, cnt - base);
        if (tid < TILE) prs[tid] = lists[off + base + ((tid < Tact) ? tid : (Tact - 1))];
        __syncthreads();
#pragma unroll
        for (int j = 0; j < TILE; j++)
            buf[j][tid] = x[(size_t)(prs[j] >> 2) * DMODEL + tid];
        __syncthreads();

        float acc[TILE];
#pragma unroll
        for (int j = 0; j < TILE; j++) acc[j] = bias;
        for (int c = 0; c < DMODEL; c += 4) {
            const float w0 = W[(c + 0) * DMODEL], w1 = W[(c + 1) * DMODEL];
            const float w2 = W[(c + 2) * DMODEL], w3 = W[(c + 3) * DMODEL];
#pragma unroll
            for (int j = 0; j < TILE; j++) {
                float4 xv = *(const float4*)&buf[j][c];
                acc[j] += xv.x * w0 + xv.y * w1 + xv.z * w2 + xv.w * w3;
            }
        }
        __syncthreads();                  // matmul reads done; reuse buf for stats
#pragma unroll
        for (int j = 0; j < TILE; j++) buf[j][tid] = acc[j];
        __syncthreads();

        const int w = tid >> 6, lane = tid & 63;
        for (int i = 0; i < 4; i++) {
            const int j = w * 4 + i;
            float s1, s2;
            wave_stats(buf[j], lane, s1, s2);
            if (lane == 0) {
                float mu = s1 * (1.0f / DMODEL);
                mus[j] = mu;
                ivs[j] = rsqrtf(s2 * (1.0f / DMODEL) - mu * mu + 1e-5f);
            }
        }
        __syncthreads();

        for (int j = 0; j < Tact; j++) {
            float y = (acc[j] - mus[j]) * ivs[j] * g + bb;
            y = (am == 0) ? gelu_exact(y) : (am == 1 ? fmaxf(y, 0.f) : tanhf(y));
            x_pre[(size_t)prs[j] * DMODEL + tid] = y;
        }
        __syncthreads();                  // protect prs/buf before next tile
    }
}

// ---- stage B: mlp experts — chunk-parallel, single 16KB LDS buffer (overlay) ----
__global__ void __launch_bounds__(256, 8) k_mlp(
    const float* __restrict__ x_pre,
    const float* __restrict__ mw1, const float* __restrict__ mb1,
    const float* __restrict__ mw2, const float* __restrict__ mb2,
    const int* __restrict__ counts, const int* __restrict__ offsets,
    const int* __restrict__ lists, float* __restrict__ x_mlp) {
    const int e = blockIdx.x;
    const int ch = blockIdx.z;
    const int chunks = 2 + (e >> 2);       // hid = 256*chunks
    if (ch >= chunks) return;
    const int cnt = counts[16 + e];
    const int off = offsets[16 + e];
    const int hbase = ch * 256;
    const bool is_gelu = ((e & 1) == 0);
    const int tid = threadIdx.x;
    const float hb = mb1[e * HMAX + hbase + tid];
    const float ob = (ch == 0) ? mb2[e * DMODEL + tid] : 0.0f;
    const float* W1 = mw1 + (size_t)e * DMODEL * HMAX + hbase + tid;
    const float* W2 = mw2 + (size_t)e * HMAX * DMODEL + (size_t)hbase * DMODEL + tid;

    __shared__ int prs[TILE];
    __shared__ float buf[TILE][DMODEL];   // x_pre stage, then midc (overlaid)

    for (int base = blockIdx.y * TILE; base < cnt; base += YBLK * TILE) {
        const int Tact = min(TILE, cnt - base);
        if (tid < TILE) prs[tid] = lists[NPAIR + off + base + ((tid < Tact) ? tid : (Tact - 1))];
        __syncthreads();
#pragma unroll
        for (int j = 0; j < TILE; j++)
            buf[j][tid] = x_pre[(size_t)prs[j] * DMODEL + tid];
        __syncthreads();

        // matmul1: this chunk's 256 hidden cols (into registers)
        float a[TILE];
#pragma unroll
        for (int j = 0; j < TILE; j++) a[j] = hb;
        for (int c = 0; c < DMODEL; c += 4) {
            const float w0 = W1[(size_t)(c + 0) * HMAX], w1 = W1[(size_t)(c + 1) * HMAX];
            const float w2 = W1[(size_t)(c + 2) * HMAX], w3 = W1[(size_t)(c + 3) * HMAX];
#pragma unroll
            for (int j = 0; j < TILE; j++) {
                float4 xv = *(const float4*)&buf[j][c];
                a[j] += xv.x * w0 + xv.y * w1 + xv.z * w2 + xv.w * w3;
            }
        }
        __syncthreads();                  // x_pre reads done; reuse buf for mid
#pragma unroll
        for (int j = 0; j < TILE; j++)
            buf[j][tid] = is_gelu ? gelu_exact(a[j]) : fmaxf(a[j], 0.f);
        __syncthreads();

        // matmul2 partial: this chunk's contribution to all 256 output cols
        float o[TILE];
#pragma unroll
        for (int j = 0; j < TILE; j++) o[j] = ob;
        for (int h = 0; h < DMODEL; h += 4) {
            const float v0 = W2[(size_t)(h + 0) * DMODEL], v1 = W2[(size_t)(h + 1) * DMODEL];
            const float v2 = W2[(size_t)(h + 2) * DMODEL], v3 = W2[(size_t)(h + 3) * DMODEL];
#pragma unroll
            for (int j = 0; j < TILE; j++) {
                float4 mv = *(const float4*)&buf[j][h];
                o[j] += mv.x * v0 + mv.y * v1 + mv.z * v2 + mv.w * v3;
            }
        }
        for (int j = 0; j < Tact; j++)
            atomicAdd(&x_mlp[(size_t)prs[j] * DMODEL + tid], o[j]);
        __syncthreads();                  // protect prs/buf before next tile
    }
}

// ---- stage C: post experts — Linear (+LN if even); single 16KB LDS buffer ----
__global__ void __launch_bounds__(256, 8) k_post(
    const float* __restrict__ x_mlp,
    const float* __restrict__ qw, const float* __restrict__ qb,
    const float* __restrict__ qg, const float* __restrict__ qbb,
    const float* __restrict__ top_val,
    const int* __restrict__ counts, const int* __restrict__ offsets,
    const int* __restrict__ lists, float* __restrict__ out) {
    const int e = blockIdx.x;
    const int cnt = counts[32 + e];
    const int off = offsets[32 + e];
    const int tid = threadIdx.x;
    const float bias = qb[e * DMODEL + tid];
    const bool has_ln = ((e & 1) == 0);
    const float g = has_ln ? qg[e * DMODEL + tid] : 0.f;
    const float bb = has_ln ? qbb[e * DMODEL + tid] : 0.f;
    const float* W = qw + (size_t)e * DMODEL * DMODEL + tid;

    __shared__ int prs[TILE];
    __shared__ float tvs[TILE];
    __shared__ float buf[TILE][DMODEL];   // x_mlp stage, then acc (overlaid)
    __shared__ float mus[TILE], ivs[TILE];

    for (int base = blockIdx.y * TILE; base < cnt; base += YBLK * TILE) {
        const int Tact = min(TILE, cnt - base);
        if (tid < TILE) {
            int p = lists[2 * NPAIR + off + base + ((tid < Tact) ? tid : (Tact - 1))];
            prs[tid] = p;
            tvs[tid] = top_val[p];
        }
        __syncthreads();
#pragma unroll
        for (int j = 0; j < TILE; j++)
            buf[j][tid] = x_mlp[(size_t)prs[j] * DMODEL + tid];
        __syncthreads();

        float acc[TILE];
#pragma unroll
        for (int j = 0; j < TILE; j++) acc[j] = bias;
        for (int c = 0; c < DMODEL; c += 4) {
            const float w0 = W[(c + 0) * DMODEL], w1 = W[(c + 1) * DMODEL];
            const float w2 = W[(c + 2) * DMODEL], w3 = W[(c + 3) * DMODEL];
#pragma unroll
            for (int j = 0; j < TILE; j++) {
                float4 xv = *(const float4*)&buf[j][c];
                acc[j] += xv.x * w0 + xv.y * w1 + xv.z * w2 + xv.w * w3;
            }
        }

        if (has_ln) {
            __syncthreads();
#pragma unroll
            for (int j = 0; j < TILE; j++) buf[j][tid] = acc[j];
            __syncthreads();
            const int w = tid >> 6, lane = tid & 63;
            for (int i = 0; i < 4; i++) {
                const int j = w * 4 + i;
                float s1, s2;
                wave_stats(buf[j], lane, s1, s2);
                if (lane == 0) {
                    float mu = s1 * (1.0f / DMODEL);
                    mus[j] = mu;
                    ivs[j] = rsqrtf(s2 * (1.0f / DMODEL) - mu * mu + 1e-5f);
                }
            }
            __syncthreads();
            for (int j = 0; j < Tact; j++) {
                float t = (acc[j] - mus[j]) * ivs[j] * g + bb;
                atomicAdd(&out[(size_t)(prs[j] >> 2) * DMODEL + tid], tvs[j] * t);
            }
        } else {
            for (int j = 0; j < Tact; j++)
                atomicAdd(&out[(size_t)(prs[j] >> 2) * DMODEL + tid], tvs[j] * acc[j]);
        }
        __syncthreads();                  // protect prs/tvs/buf before next tile
    }
}

// ---------------------------------------------------------------------------
extern "C" void kernel_launch(void* const* d_in, const int* in_sizes, int n_in,
                              void* d_out, int out_size, void* d_ws, size_t ws_size,
                              hipStream_t stream) {
    (void)in_sizes; (void)n_in; (void)out_size; (void)ws_size;

    const float* x    = (const float*)d_in[0];
    const float* rw1  = (const float*)d_in[1];
    const float* rb1  = (const float*)d_in[2];
    const float* rw2  = (const float*)d_in[3];
    const float* rb2  = (const float*)d_in[4];
    const float* rw3  = (const float*)d_in[5];
    const float* rb3  = (const float*)d_in[6];
    const float* temp = (const float*)d_in[7];
    const float* pw   = (const float*)d_in[8];
    const float* pb   = (const float*)d_in[9];
    const float* pg   = (const float*)d_in[10];
    const float* pbb  = (const float*)d_in[11];
    const float* mw1  = (const float*)d_in[12];
    const float* mb1  = (const float*)d_in[13];
    const float* mw2  = (const float*)d_in[14];
    const float* mb2  = (const float*)d_in[15];
    const float* qw   = (const float*)d_in[16];
    const float* qb   = (const float*)d_in[17];
    const float* qg   = (const float*)d_in[18];
    const float* qbb  = (const float*)d_in[19];

    float* out      = (float*)d_out;
    float* out_loss = out + (size_t)NTOK * DMODEL;
    float* out_pw   = out_loss + 1;

    float* freq_part = (float*)d_ws;                                  // 65536 f
    int*   top_idx   = (int*)(freq_part + (size_t)FSLOTS * PWAYS);    // 8192 i
    float* top_val   = (float*)(top_idx + NPAIR);                     // 8192 f
    int*   counts    = (int*)(top_val + NPAIR);                       // 64 i
    int*   offsets   = counts + 64;                                   // 64 i
    int*   cursors   = offsets + 64;                                  // 64 i
    int*   lists     = cursors + 64;                                  // 3*8192 i
    float* x_pre     = (float*)(lists + 3 * NPAIR);                   // 8192*256 f
    float* x_mlp     = x_pre + (size_t)NPAIR * DMODEL;                // 8192*256 f

    k_zero<<<1024, 256, 0, stream>>>(out_pw, freq_part);
    k_router_select<<<NTOK / 4, 256, 0, stream>>>(x, rw1, rb1, rw2, rb2, rw3, rb3,
                                                  temp, freq_part, top_idx, top_val, out_pw);
    k_freq_loss<<<1, 256, 0, stream>>>(freq_part, out_loss);

    k_zero2<<<1024, 256, 0, stream>>>(out, x_mlp, counts);
    k_count<<<NPAIR / 256, 256, 0, stream>>>(top_idx, counts);
    k_prefix<<<1, 64, 0, stream>>>(counts, offsets, cursors);
    k_scatter<<<NPAIR / 256, 256, 0, stream>>>(top_idx, cursors, lists);
    k_pre<<<dim3(16, YBLK), 256, 0, stream>>>(x, pw, pb, pg, pbb,
                                              counts, offsets, lists, x_pre);
    k_mlp<<<dim3(16, YBLK, 5), 256, 0, stream>>>(x_pre, mw1, mb1, mw2, mb2,
                                                 counts, offsets, lists, x_mlp);
    k_post<<<dim3(16, YBLK), 256, 0, stream>>>(x_mlp, qw, qb, qg, qbb, top_val,
                                               counts, offsets, lists, out);
}